// Round 9
// baseline (567.384 us; speedup 1.0000x reference)
//
#include <hip/hip_runtime.h>

// ---------------------------------------------------------------------------
// SemanticMemoryLatentSpace, fully factored (see R7 header).
// R8: clock-measurement prelude fused into scan_kernel: 65536 serially
// dependent FMAs (= 262144 cycles at 4 cyc/dep-FMA). scan_dur - 346us reads
// out the true GFX clock: +109us => 2.4GHz, +270us => ~1GHz, +400us => 650MHz.
// Scan loop itself is bit-identical to R8 (clean A/B).
// ---------------------------------------------------------------------------

#define A_BOOSTF 0.012247448713915891f // 1.5*alpha (growth==0 always)

template <int CTRL>
__device__ __forceinline__ float dpp_f(float x) {
  return __int_as_float(
      __builtin_amdgcn_mov_dpp(__float_as_int(x), CTRL, 0xf, 0xf, true));
}
template <int CTRL>
__device__ __forceinline__ unsigned dpp_u(unsigned x) {
  return (unsigned)__builtin_amdgcn_mov_dpp((int)x, CTRL, 0xf, 0xf, true);
}
__device__ __forceinline__ float rdlane_f(float x, int l) {
  return __int_as_float(__builtin_amdgcn_readlane(__float_as_int(x), l));
}
__device__ __forceinline__ unsigned rdlane_u(unsigned x, int l) {
  return (unsigned)__builtin_amdgcn_readlane((int)x, l);
}
__device__ __forceinline__ float wave_sum64(float v) {
  v += dpp_f<0xB1>(v);
  v += dpp_f<0x4E>(v);
  v += dpp_f<0x124>(v);
  v += dpp_f<0x128>(v);
  return (rdlane_f(v, 0) + rdlane_f(v, 16)) + (rdlane_f(v, 32) + rdlane_f(v, 48));
}
__device__ __forceinline__ unsigned sortable(float v) {
  unsigned u = __float_as_uint(v);
  return u ^ (unsigned)(((int)u >> 31) | 0x80000000);
}
__device__ __forceinline__ float unsortable(unsigned x) {
  unsigned u = (x & 0x80000000u) ? (x ^ 0x80000000u) : ~x;
  return __uint_as_float(u);
}
__device__ __forceinline__ unsigned wave_umax64(unsigned v) {
  v = max(v, dpp_u<0xB1>(v));
  v = max(v, dpp_u<0x4E>(v));
  v = max(v, dpp_u<0x124>(v));
  v = max(v, dpp_u<0x128>(v));
  return max(max(rdlane_u(v, 0), rdlane_u(v, 16)),
             max(rdlane_u(v, 32), rdlane_u(v, 48)));
}

#define SELCOL(rowregs, cj, out)                                   \
  {                                                                \
    const int _g = (cj) >> 6, _l = (cj) & 63;                      \
    float _s = rowregs[0];                                         \
    _s = (_g == 1) ? rowregs[1] : _s;                              \
    _s = (_g == 2) ? rowregs[2] : _s;                              \
    _s = (_g == 3) ? rowregs[3] : _s;                              \
    out = rdlane_f(_s, _l);                                        \
  }

// ---------------- generic 32x32-tile fp32 GEMMs -----------------------------
__global__ __launch_bounds__(256) void gemm_nt(const float* __restrict__ A,
                                               const float* __restrict__ B,
                                               float* __restrict__ C,
                                               int N, int K) {
  __shared__ float As[32][33];
  __shared__ float Bs[32][33];
  int bx = blockIdx.x, by = blockIdx.y;
  int tid = threadIdx.x;
  int tx = tid & 15, ty = tid >> 4;
  float a00 = 0.f, a01 = 0.f, a10 = 0.f, a11 = 0.f;
  for (int k0 = 0; k0 < K; k0 += 32) {
    for (int l = tid; l < 1024; l += 256) {
      int r = l >> 5, c = l & 31;
      As[r][c] = A[(by * 32 + r) * K + k0 + c];
      Bs[r][c] = B[(bx * 32 + r) * K + k0 + c];
    }
    __syncthreads();
#pragma unroll
    for (int k = 0; k < 32; ++k) {
      float x0 = As[2 * ty][k], x1 = As[2 * ty + 1][k];
      float y0 = Bs[2 * tx][k], y1 = Bs[2 * tx + 1][k];
      a00 += x0 * y0; a01 += x0 * y1; a10 += x1 * y0; a11 += x1 * y1;
    }
    __syncthreads();
  }
  int i = by * 32 + 2 * ty, jj = bx * 32 + 2 * tx;
  C[i * N + jj] = a00;           C[i * N + jj + 1] = a01;
  C[(i + 1) * N + jj] = a10;     C[(i + 1) * N + jj + 1] = a11;
}

__global__ __launch_bounds__(256) void gemm_nn(const float* __restrict__ A,
                                               const float* __restrict__ B,
                                               float* __restrict__ C,
                                               int N, int K) {
  __shared__ float As[32][33];
  __shared__ float Bs[32][33];
  int bx = blockIdx.x, by = blockIdx.y;
  int tid = threadIdx.x;
  int tx = tid & 15, ty = tid >> 4;
  float a00 = 0.f, a01 = 0.f, a10 = 0.f, a11 = 0.f;
  for (int k0 = 0; k0 < K; k0 += 32) {
    for (int l = tid; l < 1024; l += 256) {
      int r = l >> 5, c = l & 31;
      As[r][c] = A[(by * 32 + r) * K + k0 + c];
      Bs[r][c] = B[(k0 + r) * N + bx * 32 + c];
    }
    __syncthreads();
#pragma unroll
    for (int k = 0; k < 32; ++k) {
      float x0 = As[2 * ty][k], x1 = As[2 * ty + 1][k];
      float y0 = Bs[k][2 * tx], y1 = Bs[k][2 * tx + 1];
      a00 += x0 * y0; a01 += x0 * y1; a10 += x1 * y0; a11 += x1 * y1;
    }
    __syncthreads();
  }
  int i = by * 32 + 2 * ty, jj = bx * 32 + 2 * tx;
  C[i * N + jj] = a00;           C[i * N + jj + 1] = a01;
  C[(i + 1) * N + jj] = a10;     C[(i + 1) * N + jj + 1] = a11;
}

__global__ __launch_bounds__(256) void final_gemm(const float* __restrict__ G,
                                                  const float* __restrict__ E,
                                                  const float* __restrict__ M0,
                                                  const float* __restrict__ W,
                                                  const float* __restrict__ gS,
                                                  float* __restrict__ out) {
  __shared__ float As[32][33];
  __shared__ float Bs[32][33];
  int bx = blockIdx.x, by = blockIdx.y;
  int tid = threadIdx.x;
  int tx = tid & 15, ty = tid >> 4;
  float a00 = 0.f, a01 = 0.f, a10 = 0.f, a11 = 0.f;
  for (int k0 = 0; k0 < 512; k0 += 32) {
    for (int l = tid; l < 1024; l += 256) {
      int r = l >> 5, c = l & 31;
      As[r][c] = G[(by * 32 + r) * 512 + k0 + c] * W[k0 + c];
      Bs[r][c] = E[(k0 + r) * 384 + bx * 32 + c];
    }
    __syncthreads();
#pragma unroll
    for (int k = 0; k < 32; ++k) {
      float x0 = As[2 * ty][k], x1 = As[2 * ty + 1][k];
      float y0 = Bs[k][2 * tx], y1 = Bs[k][2 * tx + 1];
      a00 += x0 * y0; a01 += x0 * y1; a10 += x1 * y0; a11 += x1 * y1;
    }
    __syncthreads();
  }
  float gv = gS[0];
  int i = by * 32 + 2 * ty, jj = bx * 32 + 2 * tx;
  out[i * 384 + jj]         = gv * M0[i * 384 + jj]         + a00;
  out[i * 384 + jj + 1]     = gv * M0[i * 384 + jj + 1]     + a01;
  out[(i + 1) * 384 + jj]     = gv * M0[(i + 1) * 384 + jj]     + a10;
  out[(i + 1) * 384 + jj + 1] = gv * M0[(i + 1) * 384 + jj + 1] + a11;
}

__global__ __launch_bounds__(256) void prep_kernel(const float* __restrict__ E,
                                                   const float* __restrict__ M0,
                                                   const float* __restrict__ K0,
                                                   float* __restrict__ u,
                                                   float* __restrict__ Kpart) {
  __shared__ double wr[4];
  int b = blockIdx.x;
  int tid = threadIdx.x, lane = tid & 63, wv = tid >> 6;
  if (b < 128) {
    int row = b * 4 + wv;
    const float4* e4 = (const float4*)(E + row * 384);
    const float4* m4 = (const float4*)(M0 + row * 384);
    float p = 0.f;
    for (int i = lane; i < 96; i += 64) {
      float4 a = e4[i], bb = m4[i];
      p += a.x * bb.x + a.y * bb.y + a.z * bb.z + a.w * bb.w;
    }
#pragma unroll
    for (int off = 32; off; off >>= 1) p += __shfl_down(p, off);
    if (lane == 0) u[row] = p;
  } else {
    int cb = b - 128;
    const float* p = K0 + cb * 2304 + tid * 9;
    double acc = 0.0;
#pragma unroll
    for (int i = 0; i < 9; ++i) { double v = (double)p[i]; acc += v * v; }
#pragma unroll
    for (int off = 32; off; off >>= 1) acc += __shfl_down(acc, off);
    if (lane == 0) wr[wv] = acc;
    __syncthreads();
    if (tid == 0) Kpart[cb] = (float)(wr[0] + wr[1] + wr[2] + wr[3]);
  }
}

// ---------------- single-wave scan, 4 steps / DS round-trip -----------------
__global__ __launch_bounds__(64) void scan_kernel(const float* __restrict__ G,
                                                  const float* __restrict__ u,
                                                  const float* __restrict__ Kpart,
                                                  float* __restrict__ Wout,
                                                  float* __restrict__ gOut) {
  __shared__ float RAW[128 * 257];
  __shared__ float4 SLOT[512];
  __shared__ float u_sh[512];

  const int lane = threadIdx.x;
  const int ro0 = lane * 257, ro1 = (lane + 64) * 257;

  // ======== CLOCK PROBE PRELUDE: 65536 dependent FMAs = 262144 cycles ======
  {
    float a = 1.0f + (float)lane * 1e-7f;
    for (int i = 0; i < 8192; ++i) {
#pragma unroll
      for (int j = 0; j < 8; ++j) a = __builtin_fmaf(a, 1.0000001f, 1e-7f);
    }
    asm volatile("" ::"v"(a));
  }
  // =========================================================================

  ((float4*)u_sh)[lane] = ((const float4*)u)[lane];
  ((float4*)u_sh)[lane + 64] = ((const float4*)u)[lane + 64];

  float d0 = 1.f, d1 = 1.f, cn0 = 0.f, cn1 = 0.f, s0 = 0.f, s1 = 0.f;
  float n2 = wave_sum64(Kpart[lane]);
  float g = 1.f, ginv = 1.f;
  float q[4] = {0.f, 0.f, 0.f, 0.f};
  int nact = 0;

  float4 z4 = {0.f, 0.f, 0.f, 0.f};
  for (int i = lane; i < 8224; i += 64) ((float4*)RAW)[i] = z4;

  float gr[4][4], pr[4][4];
#pragma unroll
  for (int k = 0; k < 4; ++k)
#pragma unroll
    for (int m = 0; m < 4; ++m) {
      gr[k][m] = G[k * 512 + m * 64 + lane];
      pr[k][m] = G[(4 + k) * 512 + m * 64 + lane];
    }
  float r0[4] = {0.f, 0.f, 0.f, 0.f}, r1[4] = {0.f, 0.f, 0.f, 0.f};

  for (int t = 0; t < 512; t += 4) {
    const int c = t & 255;
    if (t == 256) {
      for (int i = lane; i < 8224; i += 64) ((float4*)RAW)[i] = z4;
#pragma unroll
      for (int m = 0; m < 4; ++m) q[m] = 0.f;
      __builtin_amdgcn_sched_barrier(0);
      const float* Gb = G + 256;
      float A[4][4], Bv[4][4];
      float4 SA[4], SB[4];
#pragma unroll
      for (int j = 0; j < 4; ++j) {
#pragma unroll
        for (int m = 0; m < 4; ++m) A[j][m] = Gb[j * 512 + m * 64 + lane];
        SA[j] = SLOT[j];
      }
      for (int s = 0; s < 256; s += 8) {
#pragma unroll
        for (int j = 0; j < 4; ++j) {
#pragma unroll
          for (int m = 0; m < 4; ++m)
            Bv[j][m] = Gb[(s + 4 + j) * 512 + m * 64 + lane];
          SB[j] = SLOT[s + 4 + j];
        }
#pragma unroll
        for (int j = 0; j < 4; ++j) {
          float bh = SA[j].x, wh = SA[j].y;
          int id = __float_as_int(SA[j].z);
#pragma unroll
          for (int m = 0; m < 4; ++m) {
            atomicAdd(&RAW[id * 257 + m * 64 + lane], bh * A[j][m]);
            q[m] += wh * A[j][m] * A[j][m];
          }
        }
        if (s + 8 < 256) {
#pragma unroll
          for (int j = 0; j < 4; ++j) {
#pragma unroll
            for (int m = 0; m < 4; ++m)
              A[j][m] = Gb[(s + 8 + j) * 512 + m * 64 + lane];
            SA[j] = SLOT[s + 8 + j];
          }
        }
#pragma unroll
        for (int j = 0; j < 4; ++j) {
          float bh = SB[j].x, wh = SB[j].y;
          int id = __float_as_int(SB[j].z);
#pragma unroll
          for (int m = 0; m < 4; ++m) {
            atomicAdd(&RAW[id * 257 + m * 64 + lane], bh * Bv[j][m]);
            q[m] += wh * Bv[j][m] * Bv[j][m];
          }
        }
      }
      __builtin_amdgcn_sched_barrier(0);
#pragma unroll
      for (int k = 0; k < 4; ++k) { r0[k] = RAW[ro0 + k]; r1[k] = RAW[ro1 + k]; }
      __builtin_amdgcn_sched_barrier(0);
    }

    float prn[4][4];
    {
      const int tb = (t + 8 < 512) ? (t + 8) : 508;
      const int nb2 = tb & ~255;
#pragma unroll
      for (int k = 0; k < 4; ++k) {
        const int row = (t + 8 + k < 512) ? (t + 8 + k) : 511;
#pragma unroll
        for (int m = 0; m < 4; ++m)
          prn[k][m] = G[row * 512 + nb2 + m * 64 + lane];
      }
    }

    float4 uu = *(const float4*)&u_sh[t];

    float tr[4], ren[4], qc[4];
#pragma unroll
    for (int k = 0; k < 4; ++k) {
      SELCOL(gr[k], c + k, tr[k]);
      {
        const int _g = (c + k) >> 6, _l = (c + k) & 63;
        float _s = q[0];
        _s = (_g == 1) ? q[1] : _s;
        _s = (_g == 2) ? q[2] : _s;
        _s = (_g == 3) ? q[3] : _s;
        qc[k] = rdlane_f(_s, _l);
      }
      ren[k] = __builtin_amdgcn_rcpf(__builtin_amdgcn_sqrtf(tr[k]));
    }
    float gx01, gx02, gx03, gx12, gx13, gx23;
    SELCOL(gr[0], c + 1, gx01); SELCOL(gr[0], c + 2, gx02);
    SELCOL(gr[0], c + 3, gx03); SELCOL(gr[1], c + 2, gx12);
    SELCOL(gr[1], c + 3, gx13); SELCOL(gr[2], c + 3, gx23);

    float bnewA[4], novA[4];
    int idxA[4];

#define STEP(K, RPATCH)                                                        \
    {                                                                          \
      float v0 = (lane < nact) ? s0 * ren[K] * r0[K] : -2.f;                   \
      float v1 = (lane + 64 < nact) ? s1 * ren[K] * r1[K] : -2.f;              \
      unsigned pk0 = (sortable(v0) & ~127u) | (unsigned)(127 - lane);          \
      unsigned pk1 = (sortable(v1) & ~127u) | (unsigned)(63 - lane);           \
      unsigned P = wave_umax64(max(pk0, pk1));                                 \
      int imax = 127 - (int)(P & 127u);                                        \
      float M = unsortable(P & ~127u);                                         \
      float nov = (nact == 0) ? 1.f : fminf(1.f, fmaxf(0.f, 1.f - M * M));     \
      int create = (nov > 0.7f && nact < 100) ? 1 : 0;                         \
      const int idxs = create ? nact : imax;                                   \
      const int cl = idxs & 63, hi = idxs >> 6;                                \
      float dcA = create ? 1.f : 0.95f * d0;                                   \
      float dcB = create ? 1.f : 0.95f * d1;                                   \
      float ccA = create ? tr[K]                                               \
                         : (0.9025f * cn0 + 0.095f * (d0 * r0[K]) + 0.0025f * tr[K]); \
      float ccB = create ? tr[K]                                               \
                         : (0.9025f * cn1 + 0.095f * (d1 * r1[K]) + 0.0025f * tr[K]); \
      float scA = dcA * __builtin_amdgcn_rcpf(__builtin_amdgcn_sqrtf(ccA));    \
      float scB = dcB * __builtin_amdgcn_rcpf(__builtin_amdgcn_sqrtf(ccB));    \
      bool own0 = (lane == cl) && (hi == 0);                                   \
      bool own1 = (lane == cl) && (hi == 1);                                   \
      d0 = own0 ? dcA : d0; cn0 = own0 ? ccA : cn0; s0 = own0 ? scA : s0;      \
      d1 = own1 ? dcB : d1; cn1 = own1 ? ccB : cn1; s1 = own1 ? scB : s1;      \
      float bnew = create ? 1.f                                                \
                          : 0.05f * __builtin_amdgcn_rcpf(                     \
                                        rdlane_f(hi ? dcB : dcA, cl));         \
      nact += create;                                                          \
      float pb0 = own0 ? bnew : 0.f, pb1 = own1 ? bnew : 0.f;                  \
      RPATCH                                                                   \
      bnewA[K] = bnew; novA[K] = nov; idxA[K] = idxs;                          \
      _Pragma("unroll")                                                        \
      for (int m = 0; m < 4; ++m)                                              \
        if (m * 64 + 63 >= c)                                                  \
          atomicAdd(&RAW[idxs * 257 + m * 64 + lane], bnew * gr[K][m]);        \
    }

    STEP(0, { r0[1] += pb0 * gx01; r1[1] += pb1 * gx01;
              r0[2] += pb0 * gx02; r1[2] += pb1 * gx02;
              r0[3] += pb0 * gx03; r1[3] += pb1 * gx03; })
    STEP(1, { r0[2] += pb0 * gx12; r1[2] += pb1 * gx12;
              r0[3] += pb0 * gx13; r1[3] += pb1 * gx13; })
    STEP(2, { r0[3] += pb0 * gx23; r1[3] += pb1 * gx23; })
    STEP(3, {})
#undef STEP

    if (((t + 4) & 255) != 0) {
      const int c4 = c + 4;
#pragma unroll
      for (int k = 0; k < 4; ++k) {
        r0[k] = RAW[ro0 + c4 + k];
        r1[k] = RAW[ro1 + c4 + k];
      }
    }
    __builtin_amdgcn_sched_barrier(0);

    float whA[4];
    {
      float um[4] = {uu.x, uu.y, uu.z, uu.w};
      float qeff1 = qc[1], qeff2 = qc[2], qeff3 = qc[3];
#pragma unroll
      for (int m = 0; m < 4; ++m) {
        float qe = (m == 0) ? qc[0] : ((m == 1) ? qeff1 : ((m == 2) ? qeff2 : qeff3));
        float iw = novA[m] * __builtin_amdgcn_sqrtf(novA[m]);
        float psc = 384.0f * __builtin_amdgcn_rcpf(fmaxf(tr[m], 1e-8f));
        float ccf = A_BOOSTF * iw * psc;
        float qv = g * (um[m] + qe);
        float n2n = n2 + 2.f * ccf * qv + ccf * ccf * tr[m] * tr[m];
        float kn = __builtin_amdgcn_sqrtf(n2n);
        float fct = (kn > 50.f) ? 50.f * __builtin_amdgcn_rcpf(kn) : 1.f;
        float fiv = (kn > 50.f) ? kn * 0.02f : 1.f;
        whA[m] = ccf * ginv;
        n2 = n2n * fct * fct; g *= fct; ginv *= fiv;
        if (m == 0) {
          qeff1 += whA[0] * gx01 * gx01;
          qeff2 += whA[0] * gx02 * gx02;
          qeff3 += whA[0] * gx03 * gx03;
        } else if (m == 1) {
          qeff2 += whA[1] * gx12 * gx12;
          qeff3 += whA[1] * gx13 * gx13;
        } else if (m == 2) {
          qeff3 += whA[2] * gx23 * gx23;
        }
      }
    }
#pragma unroll
    for (int m = 0; m < 4; ++m)
#pragma unroll
      for (int k = 0; k < 4; ++k) q[m] += whA[k] * gr[k][m] * gr[k][m];

    if (lane == 0) {
#pragma unroll
      for (int k = 0; k < 4; ++k) {
        float4 rec = {bnewA[k], whA[k], __int_as_float(idxA[k]), 0.f};
        SLOT[t + k] = rec;
      }
    }

#pragma unroll
    for (int k = 0; k < 4; ++k)
#pragma unroll
      for (int m = 0; m < 4; ++m) { gr[k][m] = pr[k][m]; pr[k][m] = prn[k][m]; }
  }

  for (int s2 = lane; s2 < 512; s2 += 64) Wout[s2] = SLOT[s2].y * g;
  if (lane == 0) gOut[0] = g;
}

extern "C" void kernel_launch(void* const* d_in, const int* in_sizes, int n_in,
                              void* d_out, int out_size, void* d_ws,
                              size_t ws_size, hipStream_t stream) {
  const float* E = (const float*)d_in[0];   // [512,384]
  const float* K0 = (const float*)d_in[1];  // [384,384]
  float* out = (float*)d_out;               // [512,384]

  float* G = (float*)d_ws;                  // 512*512
  float* M0 = G + 512 * 512;                // 512*384
  float* u = M0 + 512 * 384;                // 512
  float* W = u + 512;                       // 512
  float* gS = W + 512;                      // 1
  float* Kpart = gS + 1;                    // 64

  gemm_nt<<<dim3(16, 16), 256, 0, stream>>>(E, E, G, 512, 384);     // G = E E^T
  gemm_nn<<<dim3(12, 16), 256, 0, stream>>>(E, K0, M0, 384, 384);   // M0 = E K0
  prep_kernel<<<192, 256, 0, stream>>>(E, M0, K0, u, Kpart);
  scan_kernel<<<1, 64, 0, stream>>>(G, u, Kpart, W, gS);
  final_gemm<<<dim3(12, 16), 256, 0, stream>>>(G, E, M0, W, gS, out);
}